// Round 7
// baseline (82.752 us; speedup 1.0000x reference)
//
#include <hip/hip_runtime.h>
#include <hip/hip_bf16.h>

#define TT 512
#define BB 64
#define KK 10
#define DD 1024
#define CL 32   // chunk length (steps per chunk)
#define NC 16   // number of chunks

typedef unsigned char uchar;
typedef short bf16x8 __attribute__((ext_vector_type(8)));
typedef float f32x4 __attribute__((ext_vector_type(4)));

__device__ __forceinline__ unsigned f2bf(float f) {  // RNE f32 -> bf16 bits
    unsigned u = __float_as_uint(f);
    return (u + 0x7FFFu + ((u >> 16) & 1u)) >> 16;
}

__device__ __forceinline__ float max10(const float* r) {
    float m0 = fmaxf(r[0], r[1]), m1 = fmaxf(r[2], r[3]);
    float m2 = fmaxf(r[4], r[5]), m3 = fmaxf(r[6], r[7]);
    float m4 = fmaxf(r[8], r[9]);
    m0 = fmaxf(m0, m1); m2 = fmaxf(m2, m3); m0 = fmaxf(m0, m2);
    return fmaxf(m0, m4);
}

__device__ __forceinline__ float lse10(const float* r) {
    const float m = max10(r);
    float s0 = __expf(r[0] - m) + __expf(r[1] - m);
    float s1 = __expf(r[2] - m) + __expf(r[3] - m);
    float s2 = __expf(r[4] - m) + __expf(r[5] - m);
    float s3 = __expf(r[6] - m) + __expf(r[7] - m);
    float s4 = __expf(r[8] - m) + __expf(r[9] - m);
    return m + __logf(((s0 + s1) + (s2 + s3)) + s4);
}

// ---------------- Kernel A: LDS-staged MFMA emissions + lengths -------------
// 256 blocks x 512 thr; block = 128 rows x K=1024 in 8 phases of 128.
// Global loads fully coalesced (2 rows x 512B per wave-instruction), converted
// to bf16, staged into a double-buffered XOR-swizzled LDS tile; A-fragments
// read conflict-free via ds_read_b128. Block 0 also computes lengths + loss=0.
__global__ __launch_bounds__(512) void k_emissions(
    const int* __restrict__ words, const float* __restrict__ wf,
    const float* __restrict__ W, const float* __restrict__ bias,
    float* __restrict__ em, int* __restrict__ lenArr, float* loss_slot) {
    __shared__ char  Ab[2][128 * 256];   // 2 x 128 rows x 128 bf16 (64 KB)
    __shared__ uint4 Bfrag[32][64];      // 32 KB W fragment table
    __shared__ int   cnt[8][64];         // lengths scratch (block 0)

    const int tid = threadIdx.x;

    // --- B-fragment table: Bfrag[ks][lane] = W[ks*32+(lane>>4)*8+p][lane&15]
    for (int idx = tid; idx < 32 * 64; idx += 512) {
        const int ks = idx >> 6, l = idx & 63;
        const int col = l & 15, kg = l >> 4;
        unsigned u[4];
        #pragma unroll
        for (int p = 0; p < 4; ++p) {
            unsigned lo = 0, hi = 0;
            if (col < KK) {
                const int k0 = ks * 32 + kg * 8 + p * 2;
                lo = f2bf(W[(size_t)k0 * KK + col]);
                hi = f2bf(W[(size_t)(k0 + 1) * KK + col]);
            }
            u[p] = lo | (hi << 16);
        }
        Bfrag[ks][l] = make_uint4(u[0], u[1], u[2], u[3]);
    }

    const int wave = tid >> 6, lane = tid & 63;
    const int arow = lane & 15;          // A row within 16x16 tile (== C col)
    const int kg   = lane >> 4;          // k-group (and C row-group)
    const int row0blk = blockIdx.x * 128;

    // staging geometry: inst i covers tile rows i*16 + (tid>>5), cols (tid&31)*4
    const int srow = tid >> 5;           // 0..15
    const int scol = (tid & 31) * 4;     // 0..124
    const float* gbase = wf + (size_t)(row0blk + srow) * DD + scol;
    // LDS write offset (bf16, chunk-XOR swizzled; key = row&15 = srow)
    const int wr_off = srow * 256 + (((scol >> 3) ^ srow) << 4) + ((scol & 7) * 2);

    float4 st[8];
    #pragma unroll
    for (int i = 0; i < 8; ++i) st[i] = *(const float4*)(gbase + i * 16384);  // phase 0
    #pragma unroll
    for (int i = 0; i < 8; ++i) {  // cvt (truncate) + swizzled write -> buf 0
        uint2 w;
        w.x = (__float_as_uint(st[i].x) >> 16) | (__float_as_uint(st[i].y) & 0xFFFF0000u);
        w.y = (__float_as_uint(st[i].z) >> 16) | (__float_as_uint(st[i].w) & 0xFFFF0000u);
        *(uint2*)(&Ab[0][wr_off + i * 4096]) = w;
    }
    #pragma unroll
    for (int i = 0; i < 8; ++i) st[i] = *(const float4*)(gbase + 128 + i * 16384);  // phase 1
    __syncthreads();  // Bfrag + buf0 ready

    f32x4 acc = {0.f, 0.f, 0.f, 0.f};
    const int ldsrow = wave * 16 + arow;

    #pragma unroll 1
    for (int p = 0; p < 8; ++p) {
        if (p < 7) {
            if (p > 0) __syncthreads();  // all waves done reading buf[(p+1)&1]
            char* wb = Ab[(p + 1) & 1];
            #pragma unroll
            for (int i = 0; i < 8; ++i) {
                uint2 w;
                w.x = (__float_as_uint(st[i].x) >> 16) | (__float_as_uint(st[i].y) & 0xFFFF0000u);
                w.y = (__float_as_uint(st[i].z) >> 16) | (__float_as_uint(st[i].w) & 0xFFFF0000u);
                *(uint2*)(&wb[wr_off + i * 4096]) = w;
            }
            if (p < 6) {
                const float* gp = gbase + (size_t)(p + 2) * 128;
                #pragma unroll
                for (int i = 0; i < 8; ++i) st[i] = *(const float4*)(gp + i * 16384);
            }
            __syncthreads();  // new buf visible
        }
        const char* rb = &Ab[p & 1][ldsrow * 256];
        #pragma unroll
        for (int ks = 0; ks < 4; ++ks) {
            const bf16x8 a = *(const bf16x8*)(rb + (((ks * 4 + kg) ^ arow) << 4));
            union { uint4 u; bf16x8 v; } bu;
            bu.u = Bfrag[p * 4 + ks][lane];
            acc = __builtin_amdgcn_mfma_f32_16x16x32_bf16(a, bu.v, acc, 0, 0, 0);
        }
    }

    // C layout: col = lane&15, row = (lane>>4)*4 + reg  [m89]
    const int row0 = row0blk + wave * 16;
    if (arow < KK) {
        const float bk = bias[arow];
        #pragma unroll
        for (int r = 0; r < 4; ++r)
            em[(size_t)(row0 + kg * 4 + r) * KK + arow] = acc[r] + bk;
    }

    if (blockIdx.x == 0) {  // lengths + loss init (tail of block 0)
        const int b = tid & 63, seg = tid >> 6;
        int c = 0;
        for (int t = seg; t < TT; t += 8) c += (words[t * BB + b] != 0) ? 1 : 0;
        cnt[seg][b] = c;
        __syncthreads();
        if (tid < 64) {
            int s = 0;
            #pragma unroll
            for (int g = 0; g < 8; ++g) s += cnt[g][tid];
            lenArr[tid] = s;
        }
        if (tid == 0) *loss_slot = 0.f;
    }
}

// ---------------- Kernel B: per-chunk 10x10 transfer matrices ---------------
// grid 2048: blockIdx = sem*1024 + b*16 + c; 128 threads, (i,j) = tid/10,tid%10.
__global__ __launch_bounds__(128) void k_chunk(
    const float* __restrict__ em, const float* __restrict__ trans,
    const int* __restrict__ lenArr, float* __restrict__ Mlse, float* __restrict__ Mmax) {
    int id = blockIdx.x;
    const bool mx = id >= 1024; id &= 1023;
    const int b = id >> 4, c = id & 15;
    const int len = lenArr[b];
    const int s_lo = c * CL + 1;
    const int s_hi = min(c * CL + CL, len - 1);
    const int ns = s_hi - s_lo + 1;
    if (ns <= 0) return;  // identity chunk: consumers skip it

    __shared__ float Ms[KK][12];
    __shared__ float eml[CL][KK];
    const int tid = threadIdx.x;
    for (int idx = tid; idx < CL * KK; idx += 128) {
        const int sl = idx / KK, j = idx % KK;
        const int s = s_lo + sl;
        eml[sl][j] = (s <= TT - 1) ? em[((size_t)s * BB + b) * KK + j] : 0.f;
    }
    const int i = tid / KK, j = tid % KK;
    const bool act = tid < KK * KK;
    float trc[KK];
    if (act) {
        #pragma unroll
        for (int k = 0; k < KK; ++k) trc[k] = trans[k * KK + j];
    }
    __syncthreads();
    float cur = 0.f;
    if (act) { cur = trans[i * KK + j] + eml[0][j]; Ms[i][j] = cur; }
    __syncthreads();
    for (int sl = 1; sl < ns; ++sl) {
        float row[KK];
        if (act) {
            #pragma unroll
            for (int k = 0; k < KK; ++k) row[k] = Ms[i][k] + trc[k];
        }
        __syncthreads();
        if (act) {
            cur = (mx ? max10(row) : lse10(row)) + eml[sl][j];
            Ms[i][j] = cur;
        }
        __syncthreads();
    }
    if (act) {
        float* out = mx ? Mmax : Mlse;
        out[((size_t)b * NC + c) * 100 + i * KK + j] = cur;
    }
}

// ---------------- Kernel C: merged fold + hist + backtrace + loss -----------
// grid 64 (one block per batch) x 1024 threads (16 waves).
__global__ __launch_bounds__(1024) void k_crf(
    const int* __restrict__ tags, const float* __restrict__ em,
    const float* __restrict__ startv, const float* __restrict__ endv,
    const float* __restrict__ trans, const int* __restrict__ lenArr,
    const float* __restrict__ Mlse, const float* __restrict__ Mmax,
    int* __restrict__ paths, float* __restrict__ loss_slot) {
    const int b = blockIdx.x;
    const int tid = threadIdx.x;
    const int wv = tid >> 6, lane = tid & 63;
    const int len = lenArr[b];

    __shared__ float Ml[NC][100];
    __shared__ float Mm[NC][100];
    __shared__ float eml[NC][CL][KK];
    __shared__ float ub[NC][KK];
    __shared__ uchar hl[NC][CL * KK];
    __shared__ int   Fl[NC][KK];
    __shared__ int   vt[NC + 1];
    __shared__ float em0[KK];
    __shared__ float red[2];

    for (int idx = tid; idx < NC * 100; idx += 1024) {
        Ml[idx / 100][idx % 100] = Mlse[(size_t)b * NC * 100 + idx];
        Mm[idx / 100][idx % 100] = Mmax[(size_t)b * NC * 100 + idx];
    }
    for (int idx = tid; idx < NC * CL * KK; idx += 1024) {
        const int c = idx / (CL * KK), r = idx % (CL * KK);
        const int sl = r / KK, j = r % KK;
        const int s = c * CL + 1 + sl;
        eml[c][sl][j] = (s <= TT - 1) ? em[((size_t)s * BB + b) * KK + j] : 0.f;
    }
    if (tid < KK) em0[tid] = em[(size_t)b * KK + tid];
    __syncthreads();

    if (wv == 0) {  // max-plus fold -> boundary vectors + last tag
        float v[KK];
        #pragma unroll
        for (int i = 0; i < KK; ++i) v[i] = startv[i] + em0[i];
        for (int c = 0; c < NC; ++c) {
            if (lane < KK) ub[c][lane] = v[lane];
            const int s_hi = min(c * CL + CL, len - 1);
            if (s_hi >= c * CL + 1) {
                float nv = 0.f;
                if (lane < KK) {
                    float r[KK];
                    #pragma unroll
                    for (int k = 0; k < KK; ++k) r[k] = v[k] + Mm[c][k * KK + lane];
                    nv = max10(r);
                }
                #pragma unroll
                for (int i = 0; i < KK; ++i) v[i] = __shfl(nv, i);
            }
        }
        float best = v[0] + endv[0];
        int bi = 0;
        #pragma unroll
        for (int i = 1; i < KK; ++i) {
            const float x = v[i] + endv[i];
            if (x > best) { best = x; bi = i; }
        }
        if (lane == 0) vt[NC] = bi;
    } else if (wv == 1) {  // LSE fold -> denominator
        float v[KK];
        #pragma unroll
        for (int i = 0; i < KK; ++i) v[i] = startv[i] + em0[i];
        for (int c = 0; c < NC; ++c) {
            const int s_hi = min(c * CL + CL, len - 1);
            if (s_hi >= c * CL + 1) {
                float nv = 0.f;
                if (lane < KK) {
                    float r[KK];
                    #pragma unroll
                    for (int k = 0; k < KK; ++k) r[k] = v[k] + Ml[c][k * KK + lane];
                    nv = lse10(r);
                }
                #pragma unroll
                for (int i = 0; i < KK; ++i) v[i] = __shfl(nv, i);
            }
        }
        float r[KK];
        #pragma unroll
        for (int i = 0; i < KK; ++i) r[i] = v[i] + endv[i];
        if (lane == 0) red[0] = lse10(r);
    } else if (wv == 2) {  // gold-path numerator
        float part = 0.f;
        for (int t = 1 + lane; t < len; t += 64) {
            const int tp = tags[(t - 1) * BB + b];
            const int tc = tags[t * BB + b];
            part += trans[tp * KK + tc] + eml[(t - 1) >> 5][(t - 1) & 31][tc];
        }
        #pragma unroll
        for (int off = 32; off >= 1; off >>= 1) part += __shfl_xor(part, off);
        if (lane == 0) {
            const int t0 = tags[b];
            const int te = tags[(len - 1) * BB + b];
            red[1] = part + startv[t0] + em0[t0] + endv[te];
        }
    }
    __syncthreads();

    // per-chunk Viterbi re-run from exact boundary vector (wave c owns chunk c)
    {
        const int c = wv;
        const int s_hi = min(c * CL + CL, len - 1);
        const int ns = s_hi - (c * CL + 1) + 1;
        if (ns > 0) {
            float trc[KK];
            if (lane < KK) {
                #pragma unroll
                for (int i = 0; i < KK; ++i) trc[i] = trans[i * KK + lane];
            }
            float s[KK];
            #pragma unroll
            for (int i = 0; i < KK; ++i) s[i] = ub[c][i];
            for (int sl = 0; sl < ns; ++sl) {
                float best = s[0] + trc[0];
                int bi = 0;
                #pragma unroll
                for (int i = 1; i < KK; ++i) {
                    const float x = s[i] + trc[i];
                    if (x > best) { best = x; bi = i; }
                }
                float snew = 0.f;
                if (lane < KK) {
                    snew = best + eml[c][sl][lane];
                    hl[c][sl * KK + lane] = (uchar)bi;
                }
                #pragma unroll
                for (int i = 0; i < KK; ++i) s[i] = __shfl(snew, i);
            }
            if (lane < KK) {
                int cur = lane;
                for (int sl = ns - 1; sl >= 0; --sl) cur = hl[c][sl * KK + cur];
                Fl[c][lane] = cur;
            }
        }
    }
    __syncthreads();

    if (tid == 0) {  // boundary-tag fold + loss
        int cur = vt[NC];
        for (int c = NC - 1; c >= 0; --c) {
            const int s_hi = min(c * CL + CL, len - 1);
            if (s_hi >= c * CL + 1) cur = Fl[c][cur];
            vt[c] = cur;
        }
        atomicAdd(loss_slot, red[0] - red[1]);
    }
    __syncthreads();

    // emit: wave w writes path slice [32w, 32w+31]
    const int t0 = wv * CL;
    if (lane < CL) {
        const int t = t0 + lane;
        if (t >= len) paths[t * BB + b] = 0;
    }
    if (lane == 0) {
        const int a = min(t0 + CL, len - 1);
        if (a >= t0) {
            int cur = vt[wv + 1];  // = path[a]
            for (int t = a; t >= t0; --t) {
                if (t <= t0 + CL - 1) paths[t * BB + b] = cur;
                if (t > t0) cur = (int)hl[wv][(t - t0 - 1) * KK + cur];
            }
        }
    }
}

extern "C" void kernel_launch(void* const* d_in, const int* in_sizes, int n_in,
                              void* d_out, int out_size, void* d_ws, size_t ws_size,
                              hipStream_t stream) {
    const int*   words  = (const int*)d_in[0];
    const int*   tags   = (const int*)d_in[1];
    const float* wf     = (const float*)d_in[2];
    const float* W      = (const float*)d_in[3];
    const float* bias   = (const float*)d_in[4];
    const float* startv = (const float*)d_in[5];
    const float* endv   = (const float*)d_in[6];
    const float* trans  = (const float*)d_in[7];

    float* em   = (float*)d_ws;                       // 512*64*10 floats
    float* Mlse = em + 327680;                        // 64*16*100
    float* Mmax = Mlse + 102400;                      // 64*16*100
    int*   lenA = (int*)(Mmax + 102400);              // 64

    int*   paths     = (int*)d_out;                   // (T,B) int32 values
    float* loss_slot = ((float*)d_out) + TT * BB;     // scalar f32

    k_emissions<<<256, 512, 0, stream>>>(words, wf, W, bias, em, lenA, loss_slot);
    k_chunk<<<2048, 128, 0, stream>>>(em, trans, lenA, Mlse, Mmax);
    k_crf<<<64, 1024, 0, stream>>>(tags, em, startv, endv, trans, lenA,
                                   Mlse, Mmax, paths, loss_slot);
}